// Round 12
// baseline (236.805 us; speedup 1.0000x reference)
//
#include <hip/hip_runtime.h>

// GridSamplePScan: out[b,t,c] = sum_{k<=t} bilinear(images[b,k,c], base_grid + (cum[t]-cum[k]))
// B=2, L=24, C=16, H=W=64 fp32. align_corners=False, zero pad, x wrapped into [-1,1).
//
// R11 (resubmitted; GPU timeout): cooperative LDS band staging. Per-lane gathers are
// TA/latency-bound (~1000 cyc per block-k-step regardless of layout: R4/R6/R7 all
// 105-151 us). Instead, per (block,k) the block stages the union row-band of the plane
// (channels-last 4KB rows, contiguous dwordx4 loads = TA-optimal) into LDS once, and all
// samples come from LDS b128 reads.
//   - block = (b, y, q): 6 waves, wave w owns t = q + 4w. One staged band serves all 6.
//   - dynamic band: wave shfl min/max of clamped y0/y1 -> LDS -> block min/max. CAP=14.
//     band > CAP (astronomically rare) falls back to per-lane global gathers for that k.
//   - LDS XOR swizzle z^=(((z>>7)&3)<<4): stride-64B records otherwise 32-way conflict.
//     Involution; applied on both write and read; preserves 16B alignment.
//   - bid%8 = y>>3: each XCD's L2 keeps a contiguous ~3MB y-slice of all planes.
//   - cum chain: two-pass ascending, bit-matches jnp.cumsum (as in passing R4/R6/R7).

#define BB 2
#define LL 24
#define CC 16
#define HH 64
#define WW 64
#define HW (HH * WW)
#define NW 6            // waves per block
#define CAP 14          // max LDS band rows
#define ROWB 4096       // bytes per channels-last row (64 px * 64 B)

__device__ __forceinline__ int swzb(int z) {
    return z ^ (((z >> 7) & 3) << 4);   // involution: bits 7+ unchanged
}

// ---------- coordinates (exact wrap semantics; identical to passing R4/R6/R7) ----------
__device__ __forceinline__ void bilin_coords(
    float gxv0, float gyv,
    int& x0c, int& x1c, int& y0c, int& y1c,
    float& w00, float& w10, float& w01, float& w11)
{
    const float v = gxv0 + 1.0f;
    float r = v - 2.0f * truncf(v * 0.5f);   // == fmodf(v,2), exact for |v|<4
    r = (r < 0.0f) ? (r + 2.0f) : r;
    const float gxv = r - 1.0f;

    const float ix = (gxv + 1.0f) * 32.0f - 0.5f;
    const float iy = (gyv + 1.0f) * 32.0f - 0.5f;

    const float x0f = floorf(ix);
    const float y0f = floorf(iy);
    const float x1f = x0f + 1.0f;
    const float y1f = y0f + 1.0f;

    const float wx1 = ix - x0f, wx0 = 1.0f - wx1;
    const float wy1 = iy - y0f, wy0 = 1.0f - wy1;

    const bool vx0 = (x0f >= 0.0f) && (x0f <= 63.0f);
    const bool vx1 = (x1f >= 0.0f) && (x1f <= 63.0f);
    const bool vy0 = (y0f >= 0.0f) && (y0f <= 63.0f);
    const bool vy1 = (y1f >= 0.0f) && (y1f <= 63.0f);

    x0c = min(max((int)x0f, 0), WW - 1);
    x1c = min(max((int)x1f, 0), WW - 1);
    y0c = min(max((int)y0f, 0), HH - 1);
    y1c = min(max((int)y1f, 0), HH - 1);

    w00 = (vx0 && vy0) ? (wx0 * wy0) : 0.0f;
    w10 = (vx1 && vy0) ? (wx1 * wy0) : 0.0f;
    w01 = (vx0 && vy1) ? (wx0 * wy1) : 0.0f;
    w11 = (vx1 && vy1) ? (wx1 * wy1) : 0.0f;
}

// ---------- kernel 1: images [B,L,C,H,W] -> imgT [B,L,H,W,C] (measured-correct in R4/R6) ----------
__global__ __launch_bounds__(64) void transpose_kernel(
    const float* __restrict__ img, float* __restrict__ imgT)
{
    const int bid = blockIdx.x;            // (b*L + l)*H + y
    const int y = bid % HH;
    const int l = (bid / HH) % LL;
    const int b = bid / (HH * LL);
    const int x = threadIdx.x;

    const float* src = img + ((size_t)(b * LL + l) * CC) * HW + y * WW + x;
    float v[CC];
#pragma unroll
    for (int c = 0; c < CC; ++c) v[c] = src[(size_t)c * HW];

    float* dst = imgT + ((size_t)(b * LL + l) * HW + y * WW + x) * CC;
#pragma unroll
    for (int c = 0; c < CC; c += 4)
        *(float4*)(dst + c) = make_float4(v[c], v[c + 1], v[c + 2], v[c + 3]);
}

// ---------- kernel 2: cooperative LDS band staging + sampling ----------
__global__ __launch_bounds__(NW * 64) void gsps_lds(
    const float* __restrict__ flows,   // [B,L,2,H,W]
    const float* __restrict__ imgT,    // [B,L,H,W,C] 64B pixel records
    float* __restrict__ out)           // [B,L,C,H,W]
{
    __shared__ float4 buf4[CAP * 256]; // CAP rows x 4KB, swizzled
    __shared__ int bandW[NW];

    // bid = ((b*4 + q)*8 + y_lo)*8 + y_hi  -> bid%8 = y>>3 (XCD owns contiguous y-slice)
    const int bid = blockIdx.x;
    const int y_hi = bid & 7;
    int u = bid >> 3;
    const int y_lo = u & 7; u >>= 3;
    const int q = u & 3;
    const int b = u >> 2;
    const int y = (y_hi << 3) | y_lo;
    const int lane = threadIdx.x & 63;
    const int w = threadIdx.x >> 6;          // wave id 0..5
    const int t = q + 4 * w;                 // this wave's output frame
    const int kmax = q + 20;                 // largest t in block

    const float gx = -0.984375f + (float)lane * 0.03125f;
    const float gy = -0.984375f + (float)y * 0.03125f;
    const int pix = y * WW + lane;
    const float* fb = flows + (size_t)b * LL * 2 * HW + pix;

    // pass 1: cum[t] ascending (bit-matches jnp.cumsum)
    float ctx = 0.0f, cty = 0.0f;
    for (int i = 0; i <= t; ++i) {
        ctx += fb[(size_t)(2 * i) * HW];
        cty += fb[(size_t)(2 * i + 1) * HW];
    }

    float acc[CC];
#pragma unroll
    for (int c = 0; c < CC; ++c) acc[c] = 0.0f;

    float cx = 0.0f, cy = 0.0f;
    float fkx = fb[0], fky = fb[HW];

    for (int k = 0; k <= kmax; ++k) {
        cx += fkx; cy += fky;                // cum[k]
        if (k < kmax) {                      // prefetch flow[k+1]
            fkx = fb[(size_t)(2 * (k + 1)) * HW];
            fky = fb[(size_t)(2 * (k + 1) + 1) * HW];
        }

        const bool act = (t >= k);           // wave-uniform
        int x0c = 0, x1c = 0, y0c = 0, y1c = 0;
        float w00 = 0.f, w10 = 0.f, w01 = 0.f, w11 = 0.f;
        if (act)
            bilin_coords(gx + (ctx - cx), gy + (cty - cy),
                         x0c, x1c, y0c, y1c, w00, w10, w01, w11);

        // wave min/max of clamped rows -> bandW[w]
        int ymn = act ? y0c : 64;
        int ymx = act ? y1c : -1;
#pragma unroll
        for (int m = 1; m < 64; m <<= 1) {
            ymn = min(ymn, __shfl_xor(ymn, m));
            ymx = max(ymx, __shfl_xor(ymx, m));
        }
        if (lane == 0) bandW[w] = (ymn << 8) | (ymx + 1);
        __syncthreads();   // (A) band ready; also separates last iter's sampling from writes below

        int lo = 64, hx = 0;
#pragma unroll
        for (int ww = 0; ww < NW; ++ww) {
            const int bv = bandW[ww];
            lo = min(lo, bv >> 8);
            hx = max(hx, bv & 255);
        }
        const int nrows = hx - lo;           // hx = max(y1c)+1
        const bool fbk = nrows > CAP;        // block-uniform fallback flag

        const float* plane = imgT + (size_t)(b * LL + k) * (HW * CC);

        // cooperative staging: wave w loads rows lo+w, lo+w+6, lo+w+12 (3 static slots)
        const int r0g = lo + w, r1g = r0g + NW, r2g = r1g + NW;
        const bool h0 = !fbk && (r0g < lo + nrows);
        const bool h1 = !fbk && (r1g < lo + nrows);
        const bool h2 = !fbk && (r2g < lo + nrows);
        float4 rv0[4], rv1[4], rv2[4];
        if (h0) { const float* rb = plane + (size_t)r0g * 1024;
#pragma unroll
            for (int rr = 0; rr < 4; ++rr) rv0[rr] = *(const float4*)(rb + rr * 256 + lane * 4); }
        if (h1) { const float* rb = plane + (size_t)r1g * 1024;
#pragma unroll
            for (int rr = 0; rr < 4; ++rr) rv1[rr] = *(const float4*)(rb + rr * 256 + lane * 4); }
        if (h2) { const float* rb = plane + (size_t)r2g * 1024;
#pragma unroll
            for (int rr = 0; rr < 4; ++rr) rv2[rr] = *(const float4*)(rb + rr * 256 + lane * 4); }

        if (h0) {
#pragma unroll
            for (int rr = 0; rr < 4; ++rr)
                *(float4*)((char*)buf4 + (r0g - lo) * ROWB + swzb(lane * 16 + rr * 1024)) = rv0[rr];
        }
        if (h1) {
#pragma unroll
            for (int rr = 0; rr < 4; ++rr)
                *(float4*)((char*)buf4 + (r1g - lo) * ROWB + swzb(lane * 16 + rr * 1024)) = rv1[rr];
        }
        if (h2) {
#pragma unroll
            for (int rr = 0; rr < 4; ++rr)
                *(float4*)((char*)buf4 + (r2g - lo) * ROWB + swzb(lane * 16 + rr * 1024)) = rv2[rr];
        }
        __syncthreads();   // (B) band staged

        if (act) {
            if (!fbk) {
                const char* lb = (const char*)buf4;
                const int rA = (y0c - lo) * ROWB;
                const int rB = (y1c - lo) * ROWB;
                const int zx0 = x0c * 64, zx1 = x1c * 64;
#pragma unroll
                for (int j = 0; j < 4; ++j) {
                    const float4 v00 = *(const float4*)(lb + rA + swzb(zx0 + j * 16));
                    const float4 v10 = *(const float4*)(lb + rA + swzb(zx1 + j * 16));
                    const float4 v01 = *(const float4*)(lb + rB + swzb(zx0 + j * 16));
                    const float4 v11 = *(const float4*)(lb + rB + swzb(zx1 + j * 16));
                    acc[4 * j + 0] += v00.x * w00 + v10.x * w10 + v01.x * w01 + v11.x * w11;
                    acc[4 * j + 1] += v00.y * w00 + v10.y * w10 + v01.y * w01 + v11.y * w11;
                    acc[4 * j + 2] += v00.z * w00 + v10.z * w10 + v01.z * w01 + v11.z * w11;
                    acc[4 * j + 3] += v00.w * w00 + v10.w * w10 + v01.w * w01 + v11.w * w11;
                }
            } else {
                // rare fallback: per-lane global gathers (R6-measured path)
                const float* p00 = plane + (size_t)(y0c * WW + x0c) * CC;
                const float* p10 = plane + (size_t)(y0c * WW + x1c) * CC;
                const float* p01 = plane + (size_t)(y1c * WW + x0c) * CC;
                const float* p11 = plane + (size_t)(y1c * WW + x1c) * CC;
#pragma unroll
                for (int j = 0; j < 4; ++j) {
                    const float4 v00 = *(const float4*)(p00 + j * 4);
                    const float4 v10 = *(const float4*)(p10 + j * 4);
                    const float4 v01 = *(const float4*)(p01 + j * 4);
                    const float4 v11 = *(const float4*)(p11 + j * 4);
                    acc[4 * j + 0] += v00.x * w00 + v10.x * w10 + v01.x * w01 + v11.x * w11;
                    acc[4 * j + 1] += v00.y * w00 + v10.y * w10 + v01.y * w01 + v11.y * w11;
                    acc[4 * j + 2] += v00.z * w00 + v10.z * w10 + v01.z * w01 + v11.z * w11;
                    acc[4 * j + 3] += v00.w * w00 + v10.w * w10 + v01.w * w01 + v11.w * w11;
                }
            }
        }
        // no barrier here: next iter's barrier (A) separates this sampling from next staging
    }

    float* o = out + ((size_t)(b * LL + t) * CC) * HW + pix;
#pragma unroll
    for (int c = 0; c < CC; ++c) o[(size_t)c * HW] = acc[c];
}

// ---------- fallback (ws too small): R4-measured direct kernel ----------
__global__ __launch_bounds__(256) void gsps_direct(
    const float* __restrict__ flows,
    const float* __restrict__ images,  // [B,L,C,H,W]
    float* __restrict__ out)
{
    const int bid = blockIdx.x;
    const int t = (LL - 1) - (bid % LL);
    const int y = (bid / LL) % HH;
    const int b = bid / (LL * HH);
    const int x = threadIdx.x & 63;
    const int wave = threadIdx.x >> 6;
    const int cw = wave * 4;

    const float gx = -0.984375f + (float)x * 0.03125f;
    const float gy = -0.984375f + (float)y * 0.03125f;
    const int pix = y * WW + x;
    const float* fb = flows + (size_t)b * LL * 2 * HW + pix;

    float ctx = 0.0f, cty = 0.0f;
    for (int i = 0; i <= t; ++i) {
        ctx += fb[(size_t)(i * 2) * HW];
        cty += fb[(size_t)(i * 2 + 1) * HW];
    }

    float acc[4] = {0.0f, 0.0f, 0.0f, 0.0f};
    float cx = 0.0f, cy = 0.0f;
    float fxk = fb[0], fyk = fb[HW];

    for (int k = 0; k <= t; ++k) {
        cx += fxk; cy += fyk;
        if (k < t) {
            fxk = fb[(size_t)((k + 1) * 2) * HW];
            fyk = fb[(size_t)((k + 1) * 2 + 1) * HW];
        }
        int x0c, x1c, y0c, y1c; float w00, w10, w01, w11;
        bilin_coords(gx + (ctx - cx), gy + (cty - cy), x0c, x1c, y0c, y1c, w00, w10, w01, w11);

        const float* img = images + (((size_t)(b * LL + k) * CC) + cw) * HW;
#pragma unroll
        for (int c = 0; c < 4; ++c) {
            const float* pc = img + (size_t)c * HW;
            acc[c] += pc[y0c * WW + x0c] * w00 + pc[y0c * WW + x1c] * w10
                    + pc[y1c * WW + x0c] * w01 + pc[y1c * WW + x1c] * w11;
        }
    }

    float* o = out + ((size_t)(b * LL + t) * CC + cw) * HW + pix;
#pragma unroll
    for (int c = 0; c < 4; ++c) o[(size_t)c * HW] = acc[c];
}

extern "C" void kernel_launch(void* const* d_in, const int* in_sizes, int n_in,
                              void* d_out, int out_size, void* d_ws, size_t ws_size,
                              hipStream_t stream) {
    const float* flows  = (const float*)d_in[0];   // [B,L,2,H,W]
    const float* images = (const float*)d_in[1];   // [B,L,C,H,W]
    float* out = (float*)d_out;                    // [B,L,C,H,W]

    const size_t needT = (size_t)BB * LL * CC * HW * sizeof(float);  // 12.6 MB

    if (ws_size >= needT) {
        float* imgT = (float*)d_ws;
        transpose_kernel<<<BB * LL * HH, 64, 0, stream>>>(images, imgT);
        gsps_lds<<<BB * 4 * HH, NW * 64, 0, stream>>>(flows, imgT, out);
    } else {
        gsps_direct<<<BB * LL * HH, 256, 0, stream>>>(flows, images, out);
    }
}

// Round 13
// 138.613 us; speedup vs baseline: 1.7084x; 1.7084x over previous
//
#include <hip/hip_runtime.h>

// GridSamplePScan: out[b,t,c] = sum_{k<=t} bilinear(images[b,k,c], base_grid + (cum[t]-cum[k]))
// B=2, L=24, C=16, H=W=64 fp32. align_corners=False, zero pad, x wrapped into [-1,1).
//
// R13: cooperative band staging with CHANNELS-FIRST LDS (fixes R11's 5.7M bank conflicts).
//   - LDS band = [16ch][CAP=12 rows][64 floats] (48KB -> 2 blocks/CU, grid 512 = 2/CU exact).
//   - Sampling: ds_read_b32 at c*3072 + r*256 + x*4. 3072 and 256 vanish mod 32 banks ->
//     bank = x mod 32, lane-consecutive -> conflict-free (2-way free). No swizzle at all.
//     Channel term = compile-time immediate offset (c*3072 < 64KB).
//   - Staging reads ORIGINAL images layout (no transpose kernel): 256B row-segments,
//     4 segments per dwordx4 wave-instr (16 lanes x 16B each) = 16 lines/instr, TA-optimal.
//   - block = (b, y, q): 6 waves, wave w owns t = q + 4w; one staged band serves all 6.
//   - band from wave shfl min/max of clamped y0/y1 -> LDS -> block max. nrows > CAP
//     (rare) falls back to per-lane channels-first global gathers for that k.
//   - bid&7 = y>>3: each XCD's L2 keeps a ~2MB y-slice working set.
//   - cum chain: two-pass ascending, bit-matches jnp.cumsum (as in all passing rounds).

#define BB 2
#define LL 24
#define CC 16
#define HH 64
#define WW 64
#define HW (HH * WW)
#define NW 6               // waves per block
#define CAP 12             // max band rows in LDS
#define CHS (CAP * WW)     // channel slab stride in floats = 768 (3072 B)

// ---------- coordinates (exact wrap semantics; identical to passing R4/R6/R7) ----------
__device__ __forceinline__ void bilin_coords(
    float gxv0, float gyv,
    int& x0c, int& x1c, int& y0c, int& y1c,
    float& w00, float& w10, float& w01, float& w11)
{
    const float v = gxv0 + 1.0f;
    float r = v - 2.0f * truncf(v * 0.5f);   // == fmodf(v,2), exact for |v|<4
    r = (r < 0.0f) ? (r + 2.0f) : r;
    const float gxv = r - 1.0f;

    const float ix = (gxv + 1.0f) * 32.0f - 0.5f;
    const float iy = (gyv + 1.0f) * 32.0f - 0.5f;

    const float x0f = floorf(ix);
    const float y0f = floorf(iy);
    const float x1f = x0f + 1.0f;
    const float y1f = y0f + 1.0f;

    const float wx1 = ix - x0f, wx0 = 1.0f - wx1;
    const float wy1 = iy - y0f, wy0 = 1.0f - wy1;

    const bool vx0 = (x0f >= 0.0f) && (x0f <= 63.0f);
    const bool vx1 = (x1f >= 0.0f) && (x1f <= 63.0f);
    const bool vy0 = (y0f >= 0.0f) && (y0f <= 63.0f);
    const bool vy1 = (y1f >= 0.0f) && (y1f <= 63.0f);

    x0c = min(max((int)x0f, 0), WW - 1);
    x1c = min(max((int)x1f, 0), WW - 1);
    y0c = min(max((int)y0f, 0), HH - 1);
    y1c = min(max((int)y1f, 0), HH - 1);

    w00 = (vx0 && vy0) ? (wx0 * wy0) : 0.0f;
    w10 = (vx1 && vy0) ? (wx1 * wy0) : 0.0f;
    w01 = (vx0 && vy1) ? (wx0 * wy1) : 0.0f;
    w11 = (vx1 && vy1) ? (wx1 * wy1) : 0.0f;
}

__global__ __launch_bounds__(NW * 64, 4) void gsps_band(
    const float* __restrict__ flows,   // [B,L,2,H,W]
    const float* __restrict__ images,  // [B,L,C,H,W]
    float* __restrict__ out)           // [B,L,C,H,W]
{
    __shared__ float lds[CC * CHS];    // 49152 B: [c][row][x] channels-first
    __shared__ int bandW[NW];

    // bid = ((b*4 + q)*8 + y_lo)*8 + y_hi  -> bid&7 = y>>3 (XCD y-banding)
    const int bid = blockIdx.x;
    const int y_hi = bid & 7;
    int u = bid >> 3;
    const int y_lo = u & 7; u >>= 3;
    const int q = u & 3;
    const int b = u >> 2;
    const int y = (y_hi << 3) | y_lo;
    const int lane = threadIdx.x & 63;
    const int w = threadIdx.x >> 6;          // wave id 0..5
    const int t = q + 4 * w;                 // this wave's output frame
    const int kmax = q + 20;                 // largest t in block (block-uniform)

    const float gx = -0.984375f + (float)lane * 0.03125f;
    const float gy = -0.984375f + (float)y * 0.03125f;
    const int pix = y * WW + lane;
    const float* fb = flows + (size_t)b * LL * 2 * HW + pix;

    // pass 1: cum[t] ascending (bit-matches jnp.cumsum)
    float ctx = 0.0f, cty = 0.0f;
    for (int i = 0; i <= t; ++i) {
        ctx += fb[(size_t)(2 * i) * HW];
        cty += fb[(size_t)(2 * i + 1) * HW];
    }

    float acc[CC];
#pragma unroll
    for (int c = 0; c < CC; ++c) acc[c] = 0.0f;

    float cx = 0.0f, cy = 0.0f;
    float fkx = fb[0], fky = fb[HW];
    const int lg = lane >> 4;                // segment sub-index 0..3
    const int li = lane & 15;                // 16 lanes x 16B = one 256B row segment

    for (int k = 0; k <= kmax; ++k) {
        cx += fkx; cy += fky;                // cum[k]
        if (k < kmax) {                      // prefetch flow[k+1]
            fkx = fb[(size_t)(2 * (k + 1)) * HW];
            fky = fb[(size_t)(2 * (k + 1) + 1) * HW];
        }

        const bool act = (t >= k);           // wave-uniform
        int x0c = 0, x1c = 0, y0c = 0, y1c = 0;
        float w00 = 0.f, w10 = 0.f, w01 = 0.f, w11 = 0.f;
        if (act)
            bilin_coords(gx + (ctx - cx), gy + (cty - cy),
                         x0c, x1c, y0c, y1c, w00, w10, w01, w11);

        // wave min/max of clamped rows -> bandW[w]
        int ymn = act ? y0c : 64;
        int ymx = act ? y1c : -1;
#pragma unroll
        for (int m = 1; m < 64; m <<= 1) {
            ymn = min(ymn, __shfl_xor(ymn, m));
            ymx = max(ymx, __shfl_xor(ymx, m));
        }
        if (lane == 0) bandW[w] = (ymn << 8) | (ymx + 1);
        __syncthreads();   // (A) bandW ready; also fences last iter's sampling vs new writes

        int lo = 64, hx = 0;
#pragma unroll
        for (int ww = 0; ww < NW; ++ww) {
            const int bv = bandW[ww];
            lo = min(lo, bv >> 8);
            hx = max(hx, bv & 255);
        }
        const int nrows = hx - lo;           // >= 1 always (some wave active)
        const bool fbk = nrows > CAP;        // block-uniform fallback flag

        const float* imgk = images + (size_t)(b * LL + k) * (CC * HW);

        if (!fbk) {
            // cooperative staging: nrows*16 segments of 256B; 4 segments per instr.
            const int nslots = nrows * 4;
            for (int slot = w; slot < nslots; slot += NW) {
                const int seg = slot * 4 + lg;       // [0, nrows*16)
                const int c = seg & (CC - 1);
                const int r = seg >> 4;
                const float4 vv = *(const float4*)(imgk + (size_t)c * HW
                                                   + (lo + r) * WW + li * 4);
                *(float4*)&lds[c * CHS + r * WW + li * 4] = vv;
            }
        }
        __syncthreads();   // (B) band staged

        if (act) {
            if (!fbk) {
                // conflict-free b32 reads: bank = x mod 32 (c,r terms vanish mod 32)
                const int a0 = (y0c - lo) * WW + x0c;
                const int a1 = (y0c - lo) * WW + x1c;
                const int b0 = (y1c - lo) * WW + x0c;
                const int b1 = (y1c - lo) * WW + x1c;
#pragma unroll
                for (int c = 0; c < CC; ++c) {
                    const float* s = lds + c * CHS;
                    acc[c] += s[a0] * w00 + s[a1] * w10 + s[b0] * w01 + s[b1] * w11;
                }
            } else {
                // rare fallback: per-lane channels-first global gathers
                const int g00 = y0c * WW + x0c, g10 = y0c * WW + x1c;
                const int g01 = y1c * WW + x0c, g11 = y1c * WW + x1c;
#pragma unroll
                for (int c = 0; c < CC; ++c) {
                    const float* pc = imgk + (size_t)c * HW;
                    acc[c] += pc[g00] * w00 + pc[g10] * w10 + pc[g01] * w01 + pc[g11] * w11;
                }
            }
        }
        // no barrier here: next iter's (A) fences sampling vs next staging
    }

    float* o = out + ((size_t)(b * LL + t) * CC) * HW + pix;
#pragma unroll
    for (int c = 0; c < CC; ++c) o[(size_t)c * HW] = acc[c];
}

extern "C" void kernel_launch(void* const* d_in, const int* in_sizes, int n_in,
                              void* d_out, int out_size, void* d_ws, size_t ws_size,
                              hipStream_t stream) {
    const float* flows  = (const float*)d_in[0];   // [B,L,2,H,W]
    const float* images = (const float*)d_in[1];   // [B,L,C,H,W]
    float* out = (float*)d_out;                    // [B,L,C,H,W]

    const int nblk = BB * 4 * HH;                  // 512 blocks x 384 threads = 2/CU exact
    gsps_band<<<nblk, NW * 64, 0, stream>>>(flows, images, out);
}